// Round 18
// baseline (198.969 us; speedup 1.0000x reference)
//
#include <hip/hip_runtime.h>

// HamiltonianMetric: y[b] = u^T u, u = scatter(tanh(MLP(x))).
// R18: single 32-slot arena + producer/consumer waves. 256 blocks x 4 rounds
// x 32 batches. Waves 0-7 (producers): x->regs, stages 1-2 per 16-batch half
// in an 8KB scratch region (h2 hoisted to regs per half), then R11's verbatim
// dual-half stage-3 (W3 read ONCE per 32 batches). Waves 8-11 (writers):
// R14's staged-NT gram; signal 'free' right after their LDS frag reads so
// producers' next stage-3 overlaps the store DRAIN (different waves -> own
// vmcnt). Monotonic LDS counters (R17-proven protocol).

typedef __bf16 bf16_t;
typedef bf16_t bf16x8 __attribute__((ext_vector_type(8)));
typedef float  f32x4  __attribute__((ext_vector_type(4)));

#define MFMA16(a, b, c) __builtin_amdgcn_mfma_f32_16x16x32_bf16((a), (b), (c), 0, 0, 0)

constexpr int SLOT  = 4608;    // bytes per uT slot (XOR-swizzled)
constexpr int REG8  = 147456;  // 32*SLOT; 8KB stage1/2 scratch at [147456,155648)
constexpr int CTRL  = 155648;  // 3 uints: [0]=pbar, [1]=ready, [2]=free

__device__ __forceinline__ float fast_tanh(float x) {
  float cx = fminf(fmaxf(x, -30.0f), 30.0f);
  float t  = __expf(2.0f * cx);
  return (t - 1.0f) * __builtin_amdgcn_rcpf(t + 1.0f);
}

__device__ __forceinline__ bf16x8 zsel(bf16x8 f, bool keep) {
  union { bf16x8 v; unsigned int u[4]; } x;
  x.v = f;
  unsigned m = keep ? 0xFFFFFFFFu : 0u;
#pragma unroll
  for (int p = 0; p < 4; ++p) x.u[p] &= m;
  return x.v;
}

// padded position p -> (j, k): row j has j+1 valid entries, padded to 8-mult
__device__ __forceinline__ void decode_p(int p, int& j, int& k) {
  int cc = p >> 3, e = p & 7;
  int b = 0;
  while (b < 7 && cc >= 4 * (b + 1) * (b + 2)) ++b;
  int rl  = b + 1;
  int rem = cc - 4 * b * (b + 1);
  j = 8 * b + rem / rl;
  k = (rem % rl) * 8 + e;
}

__device__ __forceinline__ void ctr_arrive(unsigned* p, int lane) {
  asm volatile("s_waitcnt lgkmcnt(0)" ::: "memory");
  if (lane == 0) atomicAdd(p, 1u);
}
__device__ __forceinline__ void ctr_wait(volatile unsigned* p, unsigned tgt) {
  while (*p < tgt) __builtin_amdgcn_s_sleep(2);
  asm volatile("" ::: "memory");
  __builtin_amdgcn_sched_barrier(0);
}

// ws: [0,16384) W1t[256n][64k] | [16384,81920) W2t[256n][256k] |
//     [81920,671744) W3q tile-major: [144 t][8 kk][64 lane][8 e]
//     byte 1343488: b3p[2304] f32 (permuted triangle bias, 0 in padding)
__global__ void prep_kernel(const float* __restrict__ W1, const float* __restrict__ W2,
                            const float* __restrict__ W3, const float* __restrict__ b3,
                            char* __restrict__ wsb) {
  int tid = blockIdx.x * 512 + threadIdx.x;
  bf16_t* ws = (bf16_t*)wsb;
  if (tid < 16384) {
    int n = tid >> 6, k = tid & 63;
    ws[tid] = (bf16_t)W1[k * 256 + n];
  } else if (tid < 81920) {
    int m = tid - 16384;
    int n = m >> 8, k = m & 255;
    ws[tid] = (bf16_t)W2[k * 256 + n];
  } else if (tid < 671744) {
    int m = tid - 81920;
    int t  = m >> 12;
    int r  = m & 4095;
    int kk = r >> 9;
    int g  = (r >> 7) & 3;
    int c  = (r >> 3) & 15;
    int e  = r & 7;
    int p  = t * 16 + c;
    int k  = kk * 32 + g * 8 + e;
    int j, kd;
    decode_p(p, j, kd);
    float v = 0.f;
    if (kd <= j) {
      int n_ref = (kd == j) ? j : (64 + kd * 63 - (kd * (kd - 1)) / 2 + j - kd - 1);
      v = W3[k * 2080 + n_ref];
    }
    ws[tid] = (bf16_t)v;
  } else if (tid < 674048) {
    int p = tid - 671744;
    int j, kd;
    decode_p(p, j, kd);
    float v = 0.f;
    if (kd <= j) {
      int n_ref = (kd == j) ? j : (64 + kd * 63 - (kd * (kd - 1)) / 2 + j - kd - 1);
      v = b3[n_ref];
    }
    ((float*)(wsb + 1343488))[p] = v;
  }
}

// gram one batch: frag reads from slot (sw-swizzled), 20 MFMAs, stage y
// stripes into the (now dead) slot, 1KB-contiguous NT stores. (R14 verbatim.)
__device__ __forceinline__ void gram_store(char* slot, int sw, float* yb,
                                           int g, int c, int lane) {
  bf16x8 f0, f1, f2, f3, f2b, f3b;
#pragma unroll
  for (int ti = 0; ti < 4; ++ti) {
    int j = ti * 16 + c;
    int Q = j >> 3, s = j & 7;
    int ro = 16 * (4 * Q * (Q + 1) + s * (Q + 1));
    bf16x8 fa = *(const bf16x8*)(slot + ((ro + g * 16) ^ sw));
    if (ti == 0) f0 = zsel(fa, g * 8 <= j);
    if (ti == 1) f1 = zsel(fa, g * 8 <= j);
    if (ti == 2) f2 = fa;
    if (ti == 3) f3 = fa;
    if (ti >= 2) {
      bf16x8 fb = *(const bf16x8*)(slot + ((ro + 64 + g * 16) ^ sw));
      fb = zsel(fb, 32 + g * 8 <= j);
      if (ti == 2) f2b = fb;
      else         f3b = fb;
    }
  }
  bf16x8 fA[4] = {f0, f1, f2, f3};
  f32x4 acc[4][4];
#pragma unroll
  for (int ti = 0; ti < 4; ++ti)
#pragma unroll
    for (int tj = 0; tj < 4; ++tj) {
      f32x4 z = {0.f, 0.f, 0.f, 0.f};
      acc[ti][tj] = MFMA16(fA[ti], fA[tj], z);
    }
  acc[2][2] = MFMA16(f2b, f2b, acc[2][2]);
  acc[2][3] = MFMA16(f2b, f3b, acc[2][3]);
  acc[3][2] = MFMA16(f3b, f2b, acc[3][2]);
  acc[3][3] = MFMA16(f3b, f3b, acc[3][3]);
#pragma unroll
  for (int ti = 0; ti < 4; ++ti) {
#pragma unroll
    for (int tj = 0; tj < 4; ++tj)
#pragma unroll
      for (int r = 0; r < 4; ++r)
        *(float*)(slot + (g * 4 + r) * 256 + (tj * 16 + c) * 4) = acc[ti][tj][r];
#pragma unroll
    for (int ii = 0; ii < 4; ++ii) {
      f32x4 v = *(const f32x4*)(slot + ii * 1024 + lane * 16);
      __builtin_nontemporal_store(v, (f32x4*)(yb + ti * 1024 + ii * 256 + lane * 4));
    }
  }
}

// ---- persistent kernel: 256 blocks x 4 rounds x 32 batches, 12 waves ----
__global__ void __launch_bounds__(768, 3)
hm_kernel(const float* __restrict__ x, const float* __restrict__ b1,
          const float* __restrict__ b2, const char* __restrict__ wsb,
          float* __restrict__ out) {
  extern __shared__ char smem[];  // 155664 B
  const int tid  = threadIdx.x;
  const int w    = tid >> 6;
  const int lane = tid & 63;
  const int g    = lane >> 4;
  const int c    = lane & 15;
  const int blk  = blockIdx.x;

  const bf16_t* W1t = (const bf16_t*)wsb;
  const bf16_t* W2t = W1t + 16384;
  const bf16_t* W3q = W1t + 81920;
  const float*  b3p = (const float*)(wsb + 1343488);
  char* reg8 = smem + REG8;            // [16][512B] swz scratch
  unsigned* ctrl = (unsigned*)(smem + CTRL);

  if (tid < 3) ctrl[tid] = 0;
  __syncthreads();  // only block-wide barrier

  if (w < 8) {
    // ======================= PRODUCERS =======================
    float bias1[2], bias2[2];
#pragma unroll
    for (int ni = 0; ni < 2; ++ni) {
      int n = (w * 2 + ni) * 16 + c;
      bias1[ni] = b1[n];
      bias2[ni] = b2[n];
    }
    unsigned pb = 0;
#define PBAR() do { ++pb; ctr_arrive(&ctrl[0], lane); ctr_wait(&ctrl[0], 8u * pb); } while (0)

#pragma unroll 1
    for (int r = 0; r < 4; ++r) {
      bf16x8 aF[2][8];
#pragma unroll
      for (int h = 0; h < 2; ++h) {
        // ---- x -> regs (A-frags for this half) ----
        const float* xr = x + ((size_t)blk * 128 + r * 32 + h * 16 + c) * 64;
        f32x4 u0 = *(const f32x4*)(xr + g * 8);
        f32x4 u1 = *(const f32x4*)(xr + g * 8 + 4);
        f32x4 v0 = *(const f32x4*)(xr + 32 + g * 8);
        f32x4 v1 = *(const f32x4*)(xr + 32 + g * 8 + 4);
        bf16x8 a0, a1;
#pragma unroll
        for (int i = 0; i < 4; ++i) {
          a0[i] = (bf16_t)u0[i]; a0[4 + i] = (bf16_t)u1[i];
          a1[i] = (bf16_t)v0[i]; a1[4 + i] = (bf16_t)v1[i];
        }
        // ---- stage 1 -> h1 in reg8 ----
#pragma unroll
        for (int ni = 0; ni < 2; ++ni) {
          int n = (w * 2 + ni) * 16 + c;
          bf16x8 bw0 = *(const bf16x8*)(W1t + n * 64 + g * 8);
          bf16x8 bw1 = *(const bf16x8*)(W1t + n * 64 + 32 + g * 8);
          f32x4 acc = {0.f, 0.f, 0.f, 0.f};
          acc = MFMA16(a0, bw0, acc);
          acc = MFMA16(a1, bw1, acc);
#pragma unroll
          for (int rr = 0; rr < 4; ++rr) {
            int row = g * 4 + rr;
            float v = fast_tanh(acc[rr] + bias1[ni]);
            *(bf16_t*)(reg8 + ((row * 512 + n * 2) ^ ((row & 7) << 4))) = (bf16_t)v;
          }
        }
        PBAR();  // h1 visible
        // ---- stage 2: read h1, h2 -> regs ----
        f32x4 h2a[2];
#pragma unroll
        for (int ni = 0; ni < 2; ++ni) {
          int n = (w * 2 + ni) * 16 + c;
          f32x4 acc0 = {0.f, 0.f, 0.f, 0.f}, acc1 = {0.f, 0.f, 0.f, 0.f};
#pragma unroll
          for (int kk = 0; kk < 8; kk += 2) {
            bf16x8 p0 = *(const bf16x8*)(reg8 + ((c * 512 + kk * 64 + g * 16) ^ ((c & 7) << 4)));
            bf16x8 p1 = *(const bf16x8*)(reg8 + ((c * 512 + (kk + 1) * 64 + g * 16) ^ ((c & 7) << 4)));
            bf16x8 bw0 = *(const bf16x8*)(W2t + n * 256 + kk * 32 + g * 8);
            bf16x8 bw1 = *(const bf16x8*)(W2t + n * 256 + (kk + 1) * 32 + g * 8);
            acc0 = MFMA16(p0, bw0, acc0);
            acc1 = MFMA16(p1, bw1, acc1);
          }
          h2a[ni] = acc0 + acc1;
        }
        PBAR();  // all h1 reads done -> region reusable
        // ---- write h2 into reg8 ----
#pragma unroll
        for (int ni = 0; ni < 2; ++ni) {
          int n = (w * 2 + ni) * 16 + c;
#pragma unroll
          for (int rr = 0; rr < 4; ++rr) {
            int row = g * 4 + rr;
            float v = fast_tanh(h2a[ni][rr] + bias2[ni]);
            *(bf16_t*)(reg8 + ((row * 512 + n * 2) ^ ((row & 7) << 4))) = (bf16_t)v;
          }
        }
        PBAR();  // h2 visible
        // ---- hoist A-frags for this half ----
#pragma unroll
        for (int k = 0; k < 8; ++k)
          aF[h][k] = *(const bf16x8*)(reg8 + ((c * 512 + k * 64 + g * 16) ^ ((c & 7) << 4)));
        PBAR();  // hoist reads done
      }

      // ---- slots must be free (writers' LDS reads of round r-1 done) ----
      if (r > 0) ctr_wait(&ctrl[2], 4u * r);

      // ---- stage 3: R11 verbatim dual-half, W3 read ONCE per 32 batches ----
      {
        char* twL = smem + (g * 4) * SLOT;
        char* twH = smem + (16 + g * 4) * SLOT;
        const int swzL = (g & 7) << 4;
        const int swzH = ((4 + g) & 7) << 4;

        bf16x8 A0, A1, A2, A3, A4, A5, A6, A7; float Ab;
        bf16x8 B0, B1, B2, B3, B4, B5, B6, B7; float Bb;

#define ISSUE_T(S, TI)                                                              \
  do {                                                                              \
    int t_ = w + (TI) * 8;                                                          \
    const bf16_t* np_ = W3q + t_ * 4096 + lane * 8;                                 \
    asm volatile("global_load_dwordx4 %0, %1, off" : "=v"(S##0) : "v"(np_));            \
    asm volatile("global_load_dwordx4 %0, %1, off" : "=v"(S##1) : "v"(np_ + 512));      \
    asm volatile("global_load_dwordx4 %0, %1, off" : "=v"(S##2) : "v"(np_ + 1024));     \
    asm volatile("global_load_dwordx4 %0, %1, off" : "=v"(S##3) : "v"(np_ + 1536));     \
    asm volatile("global_load_dwordx4 %0, %1, off" : "=v"(S##4) : "v"(np_ + 2048));     \
    asm volatile("global_load_dwordx4 %0, %1, off" : "=v"(S##5) : "v"(np_ + 2560));     \
    asm volatile("global_load_dwordx4 %0, %1, off" : "=v"(S##6) : "v"(np_ + 3072));     \
    asm volatile("global_load_dwordx4 %0, %1, off" : "=v"(S##7) : "v"(np_ + 3584));     \
    asm volatile("global_load_dword %0, %1, off"   : "=v"(S##b) : "v"(b3p + t_ * 16 + c)); \
  } while (0)

#define WAIT_N(N)                                          \
  do {                                                     \
    asm volatile("s_waitcnt vmcnt(" #N ")" ::: "memory");  \
    __builtin_amdgcn_sched_barrier(0);                     \
  } while (0)

#define COMP_T(S, TI)                                                        \
  do {                                                                       \
    f32x4 al0 = {S##b, S##b, S##b, S##b}, al1 = {0.f, 0.f, 0.f, 0.f};        \
    f32x4 ah0 = {S##b, S##b, S##b, S##b}, ah1 = {0.f, 0.f, 0.f, 0.f};        \
    al0 = MFMA16(aF[0][0], S##0, al0); al1 = MFMA16(aF[0][1], S##1, al1);    \
    ah0 = MFMA16(aF[1][0], S##0, ah0); ah1 = MFMA16(aF[1][1], S##1, ah1);    \
    al0 = MFMA16(aF[0][2], S##2, al0); al1 = MFMA16(aF[0][3], S##3, al1);    \
    ah0 = MFMA16(aF[1][2], S##2, ah0); ah1 = MFMA16(aF[1][3], S##3, ah1);    \
    al0 = MFMA16(aF[0][4], S##4, al0); al1 = MFMA16(aF[0][5], S##5, al1);    \
    ah0 = MFMA16(aF[1][4], S##4, ah0); ah1 = MFMA16(aF[1][5], S##5, ah1);    \
    al0 = MFMA16(aF[0][6], S##6, al0); al1 = MFMA16(aF[0][7], S##7, al1);    \
    ah0 = MFMA16(aF[1][6], S##6, ah0); ah1 = MFMA16(aF[1][7], S##7, ah1);    \
    f32x4 asL = al0 + al1;                                                   \
    f32x4 asH = ah0 + ah1;                                                   \
    int p_ = (w + (TI) * 8) * 16 + c;                                        \
    _Pragma("unroll")                                                        \
    for (int r_ = 0; r_ < 4; ++r_) {                                         \
      float vL = fast_tanh(asL[r_]);                                         \
      *(bf16_t*)(twL + r_ * SLOT + ((p_ * 2) ^ swzL)) = (bf16_t)vL;          \
      float vH = fast_tanh(asH[r_]);                                         \
      *(bf16_t*)(twH + r_ * SLOT + ((p_ * 2) ^ swzH)) = (bf16_t)vH;          \
    }                                                                        \
  } while (0)

        ISSUE_T(A, 0);
#pragma unroll 1
        for (int pr = 0; pr < 8; ++pr) {
          ISSUE_T(B, 2 * pr + 1);
          WAIT_N(9);
          COMP_T(A, 2 * pr);
          ISSUE_T(A, 2 * pr + 2);
          WAIT_N(9);
          COMP_T(B, 2 * pr + 1);
        }
        ISSUE_T(B, 17);
        WAIT_N(9);
        COMP_T(A, 16);
        WAIT_N(0);
        COMP_T(B, 17);

#undef ISSUE_T
#undef WAIT_N
#undef COMP_T
      }
      ctr_arrive(&ctrl[1], lane);  // ready: round r's 32 slots complete
    }
#undef PBAR
  } else {
    // ======================= WRITERS =======================
    int ww = w - 8;  // 0..3
#pragma unroll 1
    for (int r = 0; r < 4; ++r) {
      ctr_wait(&ctrl[1], 8u * (r + 1));
#pragma unroll 1
      for (int bi = 0; bi < 8; ++bi) {
        int m = ww * 8 + bi;
        gram_store(smem + m * SLOT, ((m >> 2) & 7) << 4,
                   out + ((size_t)blk * 128 + r * 32 + m) * 4096,
                   g, c, lane);
      }
      ctr_arrive(&ctrl[2], lane);  // free: all my LDS reads done (stores async)
    }
  }
}

extern "C" void kernel_launch(void* const* d_in, const int* in_sizes, int n_in,
                              void* d_out, int out_size, void* d_ws, size_t ws_size,
                              hipStream_t stream) {
  (void)in_sizes; (void)n_in; (void)out_size; (void)ws_size;
  const float* x  = (const float*)d_in[0];
  const float* W1 = (const float*)d_in[1];
  const float* b1 = (const float*)d_in[2];
  const float* W2 = (const float*)d_in[3];
  const float* b2 = (const float*)d_in[4];
  const float* W3 = (const float*)d_in[5];
  const float* b3 = (const float*)d_in[6];
  char* wsb = (char*)d_ws;   // needs 1,352,704 B
  float* out = (float*)d_out;

  prep_kernel<<<1317, 512, 0, stream>>>(W1, W2, W3, b3, wsb);

  hipFuncSetAttribute((const void*)hm_kernel,
                      hipFuncAttributeMaxDynamicSharedMemorySize, 155664);
  hm_kernel<<<256, 768, 155664, stream>>>(x, b1, b2, wsb, out);
}